// Round 14
// baseline (2636.132 us; speedup 1.0000x reference)
//
#include <hip/hip_runtime.h>
#include <hip/hip_cooperative_groups.h>
#include <hip/hip_bf16.h>
#include <float.h>

namespace cg = cooperative_groups;

#define NEG_SLOPE 0.01f
typedef float v2f __attribute__((ext_vector_type(2)));
__device__ __forceinline__ float leaky(float x){ return x >= 0.0f ? x : NEG_SLOPE * x; }

#if !__has_builtin(__builtin_elementwise_fma)
#error "need __builtin_elementwise_fma"
#endif

#define RPT16(M) M(0) M(1) M(2) M(3) M(4) M(5) M(6) M(7) \
                 M(8) M(9) M(10) M(11) M(12) M(13) M(14) M(15)
#define RPT8(M) M(0) M(1) M(2) M(3) M(4) M(5) M(6) M(7)

// ---------------- kNN (proven r11 body as device function) ----------------
#define KNN_INS(bdX, biX) { bool c = cd < bdX; float tf = bdX; int ti = biX; \
    bdX = c ? cd : bdX; biX = c ? ci : biX; cd = c ? tf : cd; ci = c ? ti : ci; }
#define KNN_PROC(r, jj) { \
    float dot = qx * r.x + qy * r.y + qz * r.z; \
    float dcur = qq + r.w - 2.0f * dot; \
    if (dcur < bd7){ \
        float cd = dcur; int ci = (jj); \
        KNN_INS(bd0, bi0); KNN_INS(bd1, bi1); KNN_INS(bd2, bi2); KNN_INS(bd3, bi3); \
        KNN_INS(bd4, bi4); KNN_INS(bd5, bi5); KNN_INS(bd6, bi6); KNN_INS(bd7, bi7); \
    } }

__device__ void dev_knn(int b, int m0, const float* q, int M,
                        const float* ref, int Nr, int* idx_out, float4* sref){
    int tid = threadIdx.x;
    int m = m0 + tid;
    const float* Q = q + (size_t)b * 3 * M;
    const float* R = ref + (size_t)b * 3 * Nr;
    bool valid = (m < M);
    float qx = 0.f, qy = 0.f, qz = 0.f, qq = 0.f;
    if (valid){
        qx = Q[m]; qy = Q[M + m]; qz = Q[2 * M + m];
        qq = qx*qx + qy*qy + qz*qz;
    }
    float bd0 = FLT_MAX, bd1 = FLT_MAX, bd2 = FLT_MAX, bd3 = FLT_MAX;
    float bd4 = FLT_MAX, bd5 = FLT_MAX, bd6 = FLT_MAX, bd7 = FLT_MAX;
    int bi0 = 0, bi1 = 0, bi2 = 0, bi3 = 0, bi4 = 0, bi5 = 0, bi6 = 0, bi7 = 0;
    for (int base = 0; base < Nr; base += 1024){
        int jmax = min(1024, Nr - base);
        for (int j = tid; j < jmax; j += 256){
            float rx = R[base + j], ry = R[Nr + base + j], rz = R[2 * Nr + base + j];
            sref[j] = make_float4(rx, ry, rz, rx*rx + ry*ry + rz*rz);
        }
        __syncthreads();
        for (int j = 0; j < jmax; j += 4){
            float4 r0 = sref[j+0]; float4 r1 = sref[j+1];
            float4 r2 = sref[j+2]; float4 r3 = sref[j+3];
            KNN_PROC(r0, base + j + 0)
            KNN_PROC(r1, base + j + 1)
            KNN_PROC(r2, base + j + 2)
            KNN_PROC(r3, base + j + 3)
        }
        __syncthreads();
    }
    if (valid){
        int* o = idx_out + ((size_t)b * M + m) * 8;
        o[0] = bi0; o[1] = bi1; o[2] = bi2; o[3] = bi3;
        o[4] = bi4; o[5] = bi5; o[6] = bi6; o[7] = bi7;
    }
}

// ---------------- fused gather_sum + dual GEMM (proven r11 body) ----------------
#define RC_DECL(i) float a##i = 0.f;
#define RC_FMA(i)  a##i = fmaf(wc[i], h, fmaf(wg[i], sv, a##i));
#define RC_FIN(i)  a##i = a##i * inv + Pr[(size_t)(i) * n];
#define RC_ST(i)   O[(size_t)(i) * n] = a##i;
#define RC_STPM(i) PO[i] = a##i;

__device__ void dev_res(int b, int j0, int n,
        const float* dmc, const float* pmc, const int* idx,
        const float* wc_, const float* wg_, float* dmo, float* pmo,
        float (*tile)[65]){
    int tid = threadIdx.x, lane = tid & 63, w = tid >> 6;
    const float* PM = pmc + (size_t)b * n * 64;
    const int* ID = idx + ((size_t)b * n + j0) * 8;
    for (int c = 0; c < 16; ++c){
        int jl = w * 16 + c;
        const int* id = ID + jl * 8;
        float v = 0.f;
        #pragma unroll
        for (int k = 0; k < 8; ++k)
            v += leaky(PM[(size_t)id[k] * 64 + lane]);
        tile[jl][lane] = v;
    }
    __syncthreads();
    int j = j0 + lane;
    const float* P = dmc + (size_t)b * 64 * n + j;
    const float* sc = &tile[lane][0];
    RPT16(RC_DECL)
    for (int d = 0; d < 64; ++d){
        float h  = leaky(P[(size_t)d * n]);
        float sv = sc[d];
        const float* wc = wc_ + d * 64 + w * 16;
        const float* wg = wg_ + d * 64 + w * 16;
        RPT16(RC_FMA)
    }
    const float inv = 1.0f / 9.0f;
    const float* Pr = P + (size_t)(w * 16) * n;
    RPT16(RC_FIN)
    float* O = dmo + ((size_t)b * 64 + w * 16) * n + j;
    RPT16(RC_ST)
    float* PO = pmo + ((size_t)b * n + j) * 64 + w * 16;
    RPT16(RC_STPM)
    __syncthreads();
}

// ---------------- pool (proven r11 body) ----------------
__device__ void dev_pool(int b, int m0, int np, int nsrc,
        const float* pmc, const int* idx, float* dmo, float* pmo, float (*tile)[65]){
    int tid = threadIdx.x, lane = tid & 63, w = tid >> 6;
    const float* PM = pmc + (size_t)b * nsrc * 64;
    float* PMO = pmo + (size_t)b * np * 64;
    const int* ID = idx + ((size_t)b * np + m0) * 8;
    for (int c = 0; c < 16; ++c){
        int ml = w * 16 + c;
        const int* id = ID + ml * 8;
        float v = -FLT_MAX;
        #pragma unroll
        for (int k = 0; k < 8; ++k)
            v = fmaxf(v, PM[(size_t)id[k] * 64 + lane]);
        tile[ml][lane] = v;
        PMO[(size_t)(m0 + ml) * 64 + lane] = v;
    }
    __syncthreads();
    float* O = dmo + (size_t)b * 64 * np + m0;
    for (int c = 0; c < 16; ++c){
        int d = w * 16 + c;
        O[(size_t)d * np + lane] = tile[lane][d];
    }
    __syncthreads();
}

// ---------------- conv0 tile ----------------
__device__ void dev_conv0(int t, const float* xyz, const float* w0,
                          float* dm, float* pm){
    int b = t >> 6;
    int lane = threadIdx.x & 63, w = threadIdx.x >> 6;
    int j = ((t & 63) << 6) + lane;
    const int n = 4096;
    const float* X = xyz + (size_t)b * 3 * n;
    float x = X[j], y = X[n + j], z = X[2 * n + j];
    float* PO = pm + ((size_t)b * n + j) * 64 + w * 16;
    #pragma unroll
    for (int c = 0; c < 16; ++c){
        int oo = w * 16 + c;
        float v = w0[oo*3] * x + w0[oo*3+1] * y + w0[oo*3+2] * z;
        dm[((size_t)b * 64 + oo) * n + j] = v;
        PO[c] = v;
    }
}

// ---------------- FPS primitives (proven r10-13) ----------------
template<int CTRL>
__device__ __forceinline__ void dpp2(unsigned long long &bp){
    unsigned h = (unsigned)(bp >> 32), l = (unsigned)bp;
    unsigned th = (unsigned)__builtin_amdgcn_update_dpp(0, (int)h, CTRL, 0xF, 0xF, true);
    unsigned tl = (unsigned)__builtin_amdgcn_update_dpp(0, (int)l, CTRL, 0xF, 0xF, true);
    unsigned long long tp = ((unsigned long long)th << 32) | tl;
    bp = tp > bp ? tp : bp;
}
#define DPP_REDUCE2(bp) dpp2<0x111>(bp); dpp2<0x112>(bp); dpp2<0x114>(bp); \
    dpp2<0x118>(bp); dpp2<0x142>(bp); dpp2<0x143>(bp);

#define FPS_DECL(i) v2f px##i, py##i, pz##i, ds##i;
#define FPS_LOAD(i) { int g0 = tid + (2*(i))*T, g1 = g0 + T; \
    px##i = (v2f){X[g0], X[g1]}; py##i = (v2f){X[N+g0], X[N+g1]}; \
    pz##i = (v2f){X[2*N+g0], X[2*N+g1]}; ds##i = (v2f){1e10f, 1e10f}; }
#define FPS_PIN(i) asm volatile("" : "+v"(px##i), "+v"(py##i), "+v"(pz##i));
// dist >= 0 => float bit order == value order; ~gi larger => gi smaller, so
// u64 max == (dist >, tie: idx <) exactly.
#define FPS_UPD(i) { \
    v2f dx = px##i - l2x, dy = py##i - l2y, dz = pz##i - l2z; \
    v2f dd = __builtin_elementwise_fma(dz, dz, __builtin_elementwise_fma(dy, dy, dx*dx)); \
    float n0 = fminf(ds##i.x, dd.x), n1 = fminf(ds##i.y, dd.y); \
    ds##i = (v2f){n0, n1}; \
    unsigned long long c0 = ((unsigned long long)__float_as_uint(n0) << 32) | (unsigned)~(tid + (2*(i))*T); \
    unsigned long long c1 = ((unsigned long long)__float_as_uint(n1) << 32) | (unsigned)~(tid + (2*(i)+1)*T); \
    bp = c0 > bp ? c0 : bp; bp = c1 > bp ? c1 : bp; }

#define FPS_COMBINE(i) \
    int buf_ = (i) & 1; \
    if ((tid & 63) == 63) sred[buf_][tid >> 6] = bp; \
    __syncthreads(); \
    unsigned long long pp = sred[buf_][0]; \
    _Pragma("unroll") \
    for (int k_ = 1; k_ < 4; ++k_){ unsigned long long pk = sred[buf_][k_]; pp = pk > pp ? pk : pp; } \
    int i0 = (int)~(unsigned)pp; \
    float4 wn = sxyz[i0];

#define FPS16_ITERS(LO, HI) { \
    float* NX_ = xyz1 + (size_t)bid * 3 * 1024; \
    for (int i = (LO); i < (HI); ++i){ \
        unsigned long long bp = 0; \
        RPT8(FPS_UPD) \
        DPP_REDUCE2(bp) \
        FPS_COMBINE(i) \
        l2x = (v2f){wn.x, wn.x}; l2y = (v2f){wn.y, wn.y}; l2z = (v2f){wn.z, wn.z}; \
        if (tid == 0){ NX_[i] = wn.x; NX_[1024 + i] = wn.y; NX_[2048 + i] = wn.z; } \
    } }

#define FPS4_ITERS(LO, HI) { \
    float* NX_ = xyz2 + (size_t)bid * 3 * 256; \
    for (int i = (LO); i < (HI); ++i){ \
        unsigned long long bp = 0; \
        FPS_UPD(0) FPS_UPD(1) \
        DPP_REDUCE2(bp) \
        FPS_COMBINE(i) \
        l2x = (v2f){wn.x, wn.x}; l2y = (v2f){wn.y, wn.y}; l2z = (v2f){wn.z, wn.z}; \
        if (tid == 0){ NX_[i] = wn.x; NX_[256 + i] = wn.y; NX_[512 + i] = wn.z; } \
    } }

#define FPS1_ITERS(LO, HI) { \
    float* NX_ = xyz3 + (size_t)bid * 3 * 64; \
    for (int i = (LO); i < (HI); ++i){ \
        float dx = s1x - l2x.x, dy = s1y - l2y.x, dz = s1z - l2z.x; \
        float dd = fmaf(dz, dz, fmaf(dy, dy, dx*dx)); \
        float nd = fminf(s1d, dd); s1d = nd; \
        unsigned long long bp = ((unsigned long long)__float_as_uint(nd) << 32) | (unsigned)~tid; \
        DPP_REDUCE2(bp) \
        FPS_COMBINE(i) \
        l2x.x = wn.x; l2y.x = wn.y; l2z.x = wn.z; \
        if (tid == 0){ NX_[i] = wn.x; NX_[64 + i] = wn.y; NX_[128 + i] = wn.z; } \
    } }

// ================ THE WHOLE NETWORK: one cooperative kernel ================
__global__ void __launch_bounds__(256, 1)
k_all(const float* xyz_in, const float* w0, const float* fn_wc, const float* fn_wg,
      const float* res_wc, const float* res_wg, const float* w_last,
      float* out, char* ws)
{
    cg::grid_group grid = cg::this_grid();
    const int bid = blockIdx.x;
    const int tid = threadIdx.x;
    constexpr int T = 256;

    // ---- workspace map (bytes) ----
    float* wT    = (float*)(ws + 0UL);          // 28 * 16384
    float* dm4a  = (float*)(ws + 458752UL);
    float* dm4b  = (float*)(ws + 8847360UL);
    float* pm4a  = (float*)(ws + 17235968UL);
    float* pm4b  = (float*)(ws + 25624576UL);
    int*   idx4  = (int*)  (ws + 34013184UL);
    float* xyz1  = (float*)(ws + 35061760UL);
    float* xyz2  = (float*)(ws + 35160064UL);
    float* xyz3  = (float*)(ws + 35184640UL);
    int* i1024p  = (int*)(ws + 35190784UL);
    int* i1024s  = (int*)(ws + 35452928UL);
    int* i256p   = (int*)(ws + 35715072UL);
    int* i256s   = (int*)(ws + 35780608UL);
    int* i64p    = (int*)(ws + 35846144UL);
    int* i64s    = (int*)(ws + 35862528UL);
    // level buffers aliased into dm4b/pm4b (dead after P3)
    float* dm1a = (float*)((char*)dm4b + 0UL);
    float* dm1b = (float*)((char*)dm4b + 2097152UL);
    float* dm2a = (float*)((char*)dm4b + 4194304UL);
    float* dm2b = (float*)((char*)dm4b + 4718592UL);
    float* dm3a = (float*)((char*)dm4b + 5242880UL);
    float* dm3b = (float*)((char*)dm4b + 5373952UL);
    float* pm1a = (float*)((char*)pm4b + 0UL);
    float* pm1b = (float*)((char*)pm4b + 2097152UL);
    float* pm2a = (float*)((char*)pm4b + 4194304UL);
    float* pm2b = (float*)((char*)pm4b + 4718592UL);
    float* pm3a = (float*)((char*)pm4b + 5242880UL);
    float* pm3b = (float*)((char*)pm4b + 5373952UL);

    __shared__ __align__(16) char LB[66560];
    __shared__ unsigned long long sred[2][4];
    float4* sxyz = (float4*)LB;               // fps mirror / knn sref staging
    float (*tile)[65] = (float (*)[65])LB;    // res/pool tiles

    // persistent FPS state (live only on blocks 0-7)
    RPT8(FPS_DECL)
    v2f l2x = (v2f){0.f,0.f}, l2y = (v2f){0.f,0.f}, l2z = (v2f){0.f,0.f};
    float s1x = 0.f, s1y = 0.f, s1z = 0.f, s1d = 1e10f;

    // ---- P0: weight transpose + conv0 (dm+pm) ----
    for (int m = bid; m < 28; m += 256){
        const float* s;
        if (m < 2) s = fn_wc + (size_t)m * 4096;
        else if (m < 4) s = fn_wg + (size_t)(m - 2) * 4096;
        else if (m < 16) s = res_wc + (size_t)(m - 4) * 4096;
        else s = res_wg + (size_t)(m - 16) * 4096;
        float* o = wT + (size_t)m * 4096;
        for (int t = tid; t < 4096; t += 256){
            int oo = t >> 6, dd = t & 63;
            o[dd * 64 + oo] = s[t];
        }
    }
    for (int t = bid; t < 512; t += 256) dev_conv0(t, xyz_in, w0, dm4a, pm4a);
    grid.sync();

    // ---- P1: knn@4096 (blocks 128-255) || fps16 init + [1,342) (blocks 0-7) ----
    if (bid < 8){
        const float* X = xyz_in + (size_t)bid * 3 * 4096;
        { constexpr int N = 4096; RPT8(FPS_LOAD) RPT8(FPS_PIN) }
        for (int t = tid; t < 4096; t += 256)
            sxyz[t] = make_float4(X[t], X[4096 + t], X[8192 + t], 0.f);
        float* NX_ = xyz1 + (size_t)bid * 3 * 1024;
        if (tid == 0){ NX_[0] = X[0]; NX_[1024] = X[4096]; NX_[2048] = X[8192]; }
        l2x = (v2f){X[0], X[0]}; l2y = (v2f){X[4096], X[4096]}; l2z = (v2f){X[8192], X[8192]};
        __syncthreads();
        FPS16_ITERS(1, 342)
    } else if (bid >= 128){
        int u = bid - 128;
        dev_knn(u >> 4, (u & 15) << 8, xyz_in, 4096, xyz_in, 4096, idx4, sxyz);
    }
    grid.sync();

    // ---- P2: res@4096 #1 || fps16 [342,683) ----
    if (bid < 8){ FPS16_ITERS(342, 683) }
    else {
        for (int t = bid - 8; t < 512; t += 248)
            dev_res(t >> 6, (t & 63) << 6, 4096, dm4a, pm4a, idx4,
                    wT + 0 * 4096, wT + 2 * 4096, dm4b, pm4b, tile);
    }
    grid.sync();

    // ---- P3: res@4096 #2 || fps16 [683,1024) (done) ----
    if (bid < 8){ FPS16_ITERS(683, 1024) }
    else {
        for (int t = bid - 8; t < 512; t += 248)
            dev_res(t >> 6, (t & 63) << 6, 4096, dm4b, pm4b, idx4,
                    wT + 1 * 4096, wT + 3 * 4096, dm4a, pm4a, tile);
    }
    grid.sync();

    // ---- P4: fps4 init + [1,65) || knn(1024,4096) || knn(1024,1024) ----
    if (bid < 8){
        const float* X = xyz1 + (size_t)bid * 3 * 1024;
        { constexpr int N = 1024; FPS_LOAD(0) FPS_LOAD(1) FPS_PIN(0) FPS_PIN(1) }
        for (int t = tid; t < 1024; t += 256)
            sxyz[t] = make_float4(X[t], X[1024 + t], X[2048 + t], 0.f);
        float* NX_ = xyz2 + (size_t)bid * 3 * 256;
        if (tid == 0){ NX_[0] = X[0]; NX_[256] = X[1024]; NX_[512] = X[2048]; }
        l2x = (v2f){X[0], X[0]}; l2y = (v2f){X[1024], X[1024]}; l2z = (v2f){X[2048], X[2048]};
        __syncthreads();
        FPS4_ITERS(1, 65)
    } else if (bid < 40){
        int u = bid - 8;
        dev_knn(u >> 2, (u & 3) << 8, xyz1, 1024, xyz_in, 4096, i1024p, sxyz);
    } else if (bid < 72){
        int u = bid - 40;
        dev_knn(u >> 2, (u & 3) << 8, xyz1, 1024, xyz1, 1024, i1024s, sxyz);
    }
    grid.sync();

    // ---- P5: pool@1024 || fps4 [65,129) ----
    if (bid < 8){ FPS4_ITERS(65, 129) }
    else if (bid < 136){
        int u = bid - 8;
        dev_pool(u >> 4, (u & 15) << 6, 1024, 4096, pm4a, i1024p, dm1a, pm1a, tile);
    }
    grid.sync();

    // ---- P6: res@1024 #1 || fps4 [129,193) ----
    if (bid < 8){ FPS4_ITERS(129, 193) }
    else if (bid < 136){
        int u = bid - 8;
        dev_res(u >> 4, (u & 15) << 6, 1024, dm1a, pm1a, i1024s,
                wT + 4 * 4096, wT + 16 * 4096, dm1b, pm1b, tile);
    }
    grid.sync();

    // ---- P7: res@1024 #2 || fps4 [193,256) (done) ----
    if (bid < 8){ FPS4_ITERS(193, 256) }
    else if (bid < 136){
        int u = bid - 8;
        dev_res(u >> 4, (u & 15) << 6, 1024, dm1b, pm1b, i1024s,
                wT + 5 * 4096, wT + 17 * 4096, dm1a, pm1a, tile);
    }
    grid.sync();

    // ---- P8: res@1024 #3 || fps1 init + [1,33) || knn(256,1024) || knn(256,256) ----
    if (bid < 8){
        const float* X2 = xyz2 + (size_t)bid * 3 * 256;
        for (int t = tid; t < 256; t += 256)
            sxyz[t] = make_float4(X2[t], X2[256 + t], X2[512 + t], 0.f);
        s1x = X2[tid]; s1y = X2[256 + tid]; s1z = X2[512 + tid]; s1d = 1e10f;
        asm volatile("" : "+v"(s1x), "+v"(s1y), "+v"(s1z));
        float* NX_ = xyz3 + (size_t)bid * 3 * 64;
        if (tid == 0){ NX_[0] = X2[0]; NX_[64] = X2[256]; NX_[128] = X2[512]; }
        l2x.x = X2[0]; l2y.x = X2[256]; l2z.x = X2[512];
        __syncthreads();
        FPS1_ITERS(1, 33)
    } else if (bid < 136){
        int u = bid - 8;
        dev_res(u >> 4, (u & 15) << 6, 1024, dm1a, pm1a, i1024s,
                wT + 6 * 4096, wT + 18 * 4096, dm1b, pm1b, tile);
    } else if (bid < 144){
        dev_knn(bid - 136, 0, xyz2, 256, xyz1, 1024, i256p, sxyz);
    } else if (bid < 152){
        dev_knn(bid - 144, 0, xyz2, 256, xyz2, 256, i256s, sxyz);
    }
    grid.sync();

    // ---- P9: res@1024 #4 || fps1 [33,64) (done) ----
    if (bid < 8){ FPS1_ITERS(33, 64) }
    else if (bid < 136){
        int u = bid - 8;
        dev_res(u >> 4, (u & 15) << 6, 1024, dm1b, pm1b, i1024s,
                wT + 7 * 4096, wT + 19 * 4096, dm1a, pm1a, tile);
    }
    grid.sync();

    // ---- P10: pool@256 || knn(64,256) || knn(64,64) ----
    if (bid >= 8 && bid < 40){
        int u = bid - 8;
        dev_pool(u >> 2, (u & 3) << 6, 256, 1024, pm1a, i256p, dm2a, pm2a, tile);
    } else if (bid >= 40 && bid < 48){
        dev_knn(bid - 40, 0, xyz3, 64, xyz2, 256, i64p, sxyz);
    } else if (bid >= 48 && bid < 56){
        dev_knn(bid - 48, 0, xyz3, 64, xyz3, 64, i64s, sxyz);
    }
    grid.sync();

    // ---- P11-P14: res@256 x4 (blocks 8-39) ----
    if (bid >= 8 && bid < 40){
        int u = bid - 8;
        dev_res(u >> 2, (u & 3) << 6, 256, dm2a, pm2a, i256s,
                wT + 8 * 4096, wT + 20 * 4096, dm2b, pm2b, tile);
    }
    grid.sync();
    if (bid >= 8 && bid < 40){
        int u = bid - 8;
        dev_res(u >> 2, (u & 3) << 6, 256, dm2b, pm2b, i256s,
                wT + 9 * 4096, wT + 21 * 4096, dm2a, pm2a, tile);
    }
    grid.sync();
    if (bid >= 8 && bid < 40){
        int u = bid - 8;
        dev_res(u >> 2, (u & 3) << 6, 256, dm2a, pm2a, i256s,
                wT + 10 * 4096, wT + 22 * 4096, dm2b, pm2b, tile);
    }
    grid.sync();
    if (bid >= 8 && bid < 40){
        int u = bid - 8;
        dev_res(u >> 2, (u & 3) << 6, 256, dm2b, pm2b, i256s,
                wT + 11 * 4096, wT + 23 * 4096, dm2a, pm2a, tile);
    }
    grid.sync();

    // ---- P15: pool@64 (blocks 8-15) ----
    if (bid >= 8 && bid < 16)
        dev_pool(bid - 8, 0, 64, 256, pm2a, i64p, dm3a, pm3a, tile);
    grid.sync();

    // ---- P16-P19: res@64 x4 (blocks 8-15) ----
    if (bid >= 8 && bid < 16)
        dev_res(bid - 8, 0, 64, dm3a, pm3a, i64s,
                wT + 12 * 4096, wT + 24 * 4096, dm3b, pm3b, tile);
    grid.sync();
    if (bid >= 8 && bid < 16)
        dev_res(bid - 8, 0, 64, dm3b, pm3b, i64s,
                wT + 13 * 4096, wT + 25 * 4096, dm3a, pm3a, tile);
    grid.sync();
    if (bid >= 8 && bid < 16)
        dev_res(bid - 8, 0, 64, dm3a, pm3a, i64s,
                wT + 14 * 4096, wT + 26 * 4096, dm3b, pm3b, tile);
    grid.sync();
    if (bid >= 8 && bid < 16)
        dev_res(bid - 8, 0, 64, dm3b, pm3b, i64s,
                wT + 15 * 4096, wT + 27 * 4096, dm3a, pm3a, tile);
    grid.sync();

    // ---- P20: final (blocks 0-7) ----
    if (bid < 8 && tid < 64){
        const float* P = dm3a + (size_t)bid * 64 * 64;
        float acc = 0.f;
        for (int d = 0; d < 64; ++d) acc += w_last[d] * leaky(P[d * 64 + tid]);
        out[(size_t)bid * 64 + tid] = acc;
    }
}

extern "C" void kernel_launch(void* const* d_in, const int* in_sizes, int n_in,
                              void* d_out, int out_size, void* d_ws, size_t ws_size,
                              hipStream_t stream){
    const float* xyz_in  = (const float*)d_in[0];
    const float* w0      = (const float*)d_in[1];
    const float* fn_wc   = (const float*)d_in[2];
    const float* fn_wg   = (const float*)d_in[3];
    const float* res_wc  = (const float*)d_in[4];
    const float* res_wg  = (const float*)d_in[5];
    const float* w_last  = (const float*)d_in[6];
    float* out = (float*)d_out;
    char* ws = (char*)d_ws;

    void* args[] = {
        (void*)&xyz_in, (void*)&w0, (void*)&fn_wc, (void*)&fn_wg,
        (void*)&res_wc, (void*)&res_wg, (void*)&w_last, (void*)&out, (void*)&ws
    };
    hipLaunchCooperativeKernel((const void*)k_all, dim3(256), dim3(256),
                               args, 0, stream);
}

// Round 15
// 1674.683 us; speedup vs baseline: 1.5741x; 1.5741x over previous
//
#include <hip/hip_runtime.h>
#include <hip/hip_bf16.h>
#include <float.h>

#define NEG_SLOPE 0.01f
typedef float v2f __attribute__((ext_vector_type(2)));
__device__ __forceinline__ float leaky(float x){ return x >= 0.0f ? x : NEG_SLOPE * x; }

#if !__has_builtin(__builtin_elementwise_fma)
#error "need __builtin_elementwise_fma"
#endif

#define RPT16(M) M(0) M(1) M(2) M(3) M(4) M(5) M(6) M(7) \
                 M(8) M(9) M(10) M(11) M(12) M(13) M(14) M(15)
#define RPT8(M) M(0) M(1) M(2) M(3) M(4) M(5) M(6) M(7)

// ================= shared device bodies (verbatim r13/r14, all proven) =================
#define KNN_INS(bdX, biX) { bool c = cd < bdX; float tf = bdX; int ti = biX; \
    bdX = c ? cd : bdX; biX = c ? ci : biX; cd = c ? tf : cd; ci = c ? ti : ci; }
#define KNN_PROC(r, jj) { \
    float dot = qx * r.x + qy * r.y + qz * r.z; \
    float dcur = qq + r.w - 2.0f * dot; \
    if (dcur < bd7){ \
        float cd = dcur; int ci = (jj); \
        KNN_INS(bd0, bi0); KNN_INS(bd1, bi1); KNN_INS(bd2, bi2); KNN_INS(bd3, bi3); \
        KNN_INS(bd4, bi4); KNN_INS(bd5, bi5); KNN_INS(bd6, bi6); KNN_INS(bd7, bi7); \
    } }

__device__ void dev_knn(int b, int m0, const float* q, int M,
                        const float* ref, int Nr, int* idx_out, float4* sref){
    int tid = threadIdx.x;
    int m = m0 + tid;
    const float* Q = q + (size_t)b * 3 * M;
    const float* R = ref + (size_t)b * 3 * Nr;
    bool valid = (m < M);
    float qx = 0.f, qy = 0.f, qz = 0.f, qq = 0.f;
    if (valid){
        qx = Q[m]; qy = Q[M + m]; qz = Q[2 * M + m];
        qq = qx*qx + qy*qy + qz*qz;
    }
    float bd0 = FLT_MAX, bd1 = FLT_MAX, bd2 = FLT_MAX, bd3 = FLT_MAX;
    float bd4 = FLT_MAX, bd5 = FLT_MAX, bd6 = FLT_MAX, bd7 = FLT_MAX;
    int bi0 = 0, bi1 = 0, bi2 = 0, bi3 = 0, bi4 = 0, bi5 = 0, bi6 = 0, bi7 = 0;
    for (int base = 0; base < Nr; base += 1024){
        int jmax = min(1024, Nr - base);
        for (int j = tid; j < jmax; j += 256){
            float rx = R[base + j], ry = R[Nr + base + j], rz = R[2 * Nr + base + j];
            sref[j] = make_float4(rx, ry, rz, rx*rx + ry*ry + rz*rz);
        }
        __syncthreads();
        for (int j = 0; j < jmax; j += 4){
            float4 r0 = sref[j+0]; float4 r1 = sref[j+1];
            float4 r2 = sref[j+2]; float4 r3 = sref[j+3];
            KNN_PROC(r0, base + j + 0)
            KNN_PROC(r1, base + j + 1)
            KNN_PROC(r2, base + j + 2)
            KNN_PROC(r3, base + j + 3)
        }
        __syncthreads();
    }
    if (valid){
        int* o = idx_out + ((size_t)b * M + m) * 8;
        o[0] = bi0; o[1] = bi1; o[2] = bi2; o[3] = bi3;
        o[4] = bi4; o[5] = bi5; o[6] = bi6; o[7] = bi7;
    }
}

#define RC_DECL(i) float a##i = 0.f;
#define RC_FMA(i)  a##i = fmaf(wc[i], h, fmaf(wg[i], sv, a##i));
#define RC_FIN(i)  a##i = a##i * inv + Pr[(size_t)(i) * n];
#define RC_ST(i)   O[(size_t)(i) * n] = a##i;
#define RC_STPM(i) PO[i] = a##i;

__device__ void dev_res(int b, int j0, int n,
        const float* dmc, const float* pmc, const int* idx,
        const float* wc_, const float* wg_, float* dmo, float* pmo,
        float (*tile)[65]){
    int tid = threadIdx.x, lane = tid & 63, w = tid >> 6;
    const float* PM = pmc + (size_t)b * n * 64;
    const int* ID = idx + ((size_t)b * n + j0) * 8;
    for (int c = 0; c < 16; ++c){
        int jl = w * 16 + c;
        const int* id = ID + jl * 8;
        float v = 0.f;
        #pragma unroll
        for (int k = 0; k < 8; ++k)
            v += leaky(PM[(size_t)id[k] * 64 + lane]);
        tile[jl][lane] = v;
    }
    __syncthreads();
    int j = j0 + lane;
    const float* P = dmc + (size_t)b * 64 * n + j;
    const float* sc = &tile[lane][0];
    RPT16(RC_DECL)
    for (int d = 0; d < 64; ++d){
        float h  = leaky(P[(size_t)d * n]);
        float sv = sc[d];
        const float* wc = wc_ + d * 64 + w * 16;
        const float* wg = wg_ + d * 64 + w * 16;
        RPT16(RC_FMA)
    }
    const float inv = 1.0f / 9.0f;
    const float* Pr = P + (size_t)(w * 16) * n;
    RPT16(RC_FIN)
    float* O = dmo + ((size_t)b * 64 + w * 16) * n + j;
    RPT16(RC_ST)
    float* PO = pmo + ((size_t)b * n + j) * 64 + w * 16;
    RPT16(RC_STPM)
    __syncthreads();
}

__device__ void dev_pool(int b, int m0, int np, int nsrc,
        const float* pmc, const int* idx, float* dmo, float* pmo, float (*tile)[65]){
    int tid = threadIdx.x, lane = tid & 63, w = tid >> 6;
    const float* PM = pmc + (size_t)b * nsrc * 64;
    float* PMO = pmo + (size_t)b * np * 64;
    const int* ID = idx + ((size_t)b * np + m0) * 8;
    for (int c = 0; c < 16; ++c){
        int ml = w * 16 + c;
        const int* id = ID + ml * 8;
        float v = -FLT_MAX;
        #pragma unroll
        for (int k = 0; k < 8; ++k)
            v = fmaxf(v, PM[(size_t)id[k] * 64 + lane]);
        tile[ml][lane] = v;
        PMO[(size_t)(m0 + ml) * 64 + lane] = v;
    }
    __syncthreads();
    float* O = dmo + (size_t)b * 64 * np + m0;
    for (int c = 0; c < 16; ++c){
        int d = w * 16 + c;
        O[(size_t)d * np + lane] = tile[lane][d];
    }
    __syncthreads();
}

__device__ void dev_conv0(int t, const float* xyz, const float* w0,
                          float* dm, float* pm){
    int b = t >> 6;
    int lane = threadIdx.x & 63, w = threadIdx.x >> 6;
    int j = ((t & 63) << 6) + lane;
    const int n = 4096;
    const float* X = xyz + (size_t)b * 3 * n;
    float x = X[j], y = X[n + j], z = X[2 * n + j];
    float* PO = pm + ((size_t)b * n + j) * 64 + w * 16;
    #pragma unroll
    for (int c = 0; c < 16; ++c){
        int oo = w * 16 + c;
        float v = w0[oo*3] * x + w0[oo*3+1] * y + w0[oo*3+2] * z;
        dm[((size_t)b * 64 + oo) * n + j] = v;
        PO[c] = v;
    }
}

// ---- FPS primitives ----
template<int CTRL>
__device__ __forceinline__ void dpp2(unsigned long long &bp){
    unsigned h = (unsigned)(bp >> 32), l = (unsigned)bp;
    unsigned th = (unsigned)__builtin_amdgcn_update_dpp(0, (int)h, CTRL, 0xF, 0xF, true);
    unsigned tl = (unsigned)__builtin_amdgcn_update_dpp(0, (int)l, CTRL, 0xF, 0xF, true);
    unsigned long long tp = ((unsigned long long)th << 32) | tl;
    bp = tp > bp ? tp : bp;
}
#define DPP_REDUCE2(bp) dpp2<0x111>(bp); dpp2<0x112>(bp); dpp2<0x114>(bp); \
    dpp2<0x118>(bp); dpp2<0x142>(bp); dpp2<0x143>(bp);

#define FPS_DECL(i) v2f px##i, py##i, pz##i, ds##i;
#define FPS_LOAD(i) { int g0 = tid + (2*(i))*T, g1 = g0 + T; \
    px##i = (v2f){X[g0], X[g1]}; py##i = (v2f){X[N+g0], X[N+g1]}; \
    pz##i = (v2f){X[2*N+g0], X[2*N+g1]}; ds##i = (v2f){1e10f, 1e10f}; }
#define FPS_PIN(i) asm volatile("" : "+v"(px##i), "+v"(py##i), "+v"(pz##i));
// dist >= 0 => float bit order == value order; ~gi larger => gi smaller, so
// u64 max == (dist >, tie: idx <) exactly.
#define FPS_UPD(i) { \
    v2f dx = px##i - l2x, dy = py##i - l2y, dz = pz##i - l2z; \
    v2f dd = __builtin_elementwise_fma(dz, dz, __builtin_elementwise_fma(dy, dy, dx*dx)); \
    float n0 = fminf(ds##i.x, dd.x), n1 = fminf(ds##i.y, dd.y); \
    ds##i = (v2f){n0, n1}; \
    unsigned long long c0 = ((unsigned long long)__float_as_uint(n0) << 32) | (unsigned)~(tid + (2*(i))*T); \
    unsigned long long c1 = ((unsigned long long)__float_as_uint(n1) << 32) | (unsigned)~(tid + (2*(i)+1)*T); \
    bp = c0 > bp ? c0 : bp; bp = c1 > bp ? c1 : bp; }

#define FPS_COMBINE(i) \
    int buf_ = (i) & 1; \
    if ((tid & 63) == 63) sred[buf_][tid >> 6] = bp; \
    __syncthreads(); \
    unsigned long long pp = sred[buf_][0]; \
    _Pragma("unroll") \
    for (int k_ = 1; k_ < 4; ++k_){ unsigned long long pk = sred[buf_][k_]; pp = pk > pp ? pk : pp; } \
    int i0 = (int)~(unsigned)pp; \
    float4 wn = sxyz[i0];

// ================= LAUNCH 1: fps16 || knn@4096 || transpose || conv0 =================
__global__ void __launch_bounds__(256, 1)
k_front(const float* __restrict__ xyz_in, const float* __restrict__ w0,
        const float* __restrict__ fn_wc, const float* __restrict__ fn_wg,
        const float* __restrict__ res_wc, const float* __restrict__ res_wg,
        float* __restrict__ wT, float* __restrict__ dm4a, float* __restrict__ pm4a,
        int* __restrict__ idx4, float* __restrict__ xyz1){
    __shared__ __align__(16) char LB[66560];
    __shared__ unsigned long long sred[2][4];
    int bid = blockIdx.x, tid = threadIdx.x;
    if (bid < 8){
        // fps16: 4096 -> 1024
        float4* sxyz = (float4*)LB;
        constexpr int N = 4096, T = 256;
        const float* X = xyz_in + (size_t)bid * 3 * N;
        RPT8(FPS_DECL) RPT8(FPS_LOAD) RPT8(FPS_PIN)
        for (int t = tid; t < N; t += T)
            sxyz[t] = make_float4(X[t], X[N+t], X[2*N+t], 0.f);
        float* NX_ = xyz1 + (size_t)bid * 3 * 1024;
        if (tid == 0){ NX_[0] = X[0]; NX_[1024] = X[N]; NX_[2048] = X[2*N]; }
        v2f l2x = (v2f){X[0], X[0]}, l2y = (v2f){X[N], X[N]}, l2z = (v2f){X[2*N], X[2*N]};
        __syncthreads();
        for (int i = 1; i < 1024; ++i){
            unsigned long long bp = 0;
            RPT8(FPS_UPD)
            DPP_REDUCE2(bp)
            FPS_COMBINE(i)
            l2x = (v2f){wn.x, wn.x}; l2y = (v2f){wn.y, wn.y}; l2z = (v2f){wn.z, wn.z};
            if (tid == 0){ NX_[i] = wn.x; NX_[1024 + i] = wn.y; NX_[2048 + i] = wn.z; }
        }
    } else if (bid < 136){
        int u = bid - 8;
        dev_knn(u >> 4, (u & 15) << 8, xyz_in, 4096, xyz_in, 4096, idx4, (float4*)LB);
    } else if (bid < 164){
        int m = bid - 136;
        const float* s;
        if (m < 2) s = fn_wc + (size_t)m * 4096;
        else if (m < 4) s = fn_wg + (size_t)(m - 2) * 4096;
        else if (m < 16) s = res_wc + (size_t)(m - 4) * 4096;
        else s = res_wg + (size_t)(m - 16) * 4096;
        float* o = wT + (size_t)m * 4096;
        for (int t = tid; t < 4096; t += 256){
            int oo = t >> 6, dd = t & 63;
            o[dd * 64 + oo] = s[t];
        }
    } else {
        for (int t = bid - 164; t < 512; t += 64)
            dev_conv0(t, xyz_in, w0, dm4a, pm4a);
    }
}

// ================= LAUNCH 2: fps4 || res4096#1 || knn(1024,4096) || knn(1024,1024) =================
__global__ void __launch_bounds__(256, 1)
k_mid1(const float* __restrict__ xyz_in, const float* __restrict__ xyz1,
       const float* __restrict__ wT,
       const float* __restrict__ dm4a, const float* __restrict__ pm4a,
       const int* __restrict__ idx4,
       float* __restrict__ dm4b, float* __restrict__ pm4b,
       int* __restrict__ i1024p, int* __restrict__ i1024s,
       float* __restrict__ xyz2){
    __shared__ __align__(16) char LB[16640];
    __shared__ unsigned long long sred[2][4];
    int bid = blockIdx.x, tid = threadIdx.x;
    if (bid < 8){
        // fps4: 1024 -> 256 (multi-wave, r14-proven body)
        float4* sxyz = (float4*)LB;
        constexpr int N = 1024, T = 256;
        const float* X = xyz1 + (size_t)bid * 3 * N;
        FPS_DECL(0) FPS_DECL(1)
        FPS_LOAD(0) FPS_LOAD(1) FPS_PIN(0) FPS_PIN(1)
        for (int t = tid; t < N; t += T)
            sxyz[t] = make_float4(X[t], X[N+t], X[2*N+t], 0.f);
        float* NX_ = xyz2 + (size_t)bid * 3 * 256;
        if (tid == 0){ NX_[0] = X[0]; NX_[256] = X[N]; NX_[512] = X[2*N]; }
        v2f l2x = (v2f){X[0], X[0]}, l2y = (v2f){X[N], X[N]}, l2z = (v2f){X[2*N], X[2*N]};
        __syncthreads();
        for (int i = 1; i < 256; ++i){
            unsigned long long bp = 0;
            FPS_UPD(0) FPS_UPD(1)
            DPP_REDUCE2(bp)
            FPS_COMBINE(i)
            l2x = (v2f){wn.x, wn.x}; l2y = (v2f){wn.y, wn.y}; l2z = (v2f){wn.z, wn.z};
            if (tid == 0){ NX_[i] = wn.x; NX_[256 + i] = wn.y; NX_[512 + i] = wn.z; }
        }
    } else if (bid < 520){
        int t = bid - 8;
        dev_res(t >> 6, (t & 63) << 6, 4096, dm4a, pm4a, idx4,
                wT + 0 * 4096, wT + 2 * 4096, dm4b, pm4b, (float (*)[65])LB);
    } else if (bid < 552){
        int u = bid - 520;
        dev_knn(u >> 2, (u & 3) << 8, xyz1, 1024, xyz_in, 4096, i1024p, (float4*)LB);
    } else {
        int u = bid - 552;
        dev_knn(u >> 2, (u & 3) << 8, xyz1, 1024, xyz1, 1024, i1024s, (float4*)LB);
    }
}

// ================= LAUNCH 3: fps1 || res4096#2 || knn(256,1024) || knn(256,256) =================
__global__ void __launch_bounds__(256, 1)
k_mid2(const float* __restrict__ xyz1, const float* __restrict__ xyz2,
       const float* __restrict__ wT,
       const float* __restrict__ dm4b, const float* __restrict__ pm4b,
       const int* __restrict__ idx4,
       float* __restrict__ dm4a, float* __restrict__ pm4a,
       int* __restrict__ i256p, int* __restrict__ i256s,
       float* __restrict__ xyz3){
    __shared__ __align__(16) char LB[16640];
    __shared__ unsigned long long sred[2][4];
    int bid = blockIdx.x, tid = threadIdx.x;
    if (bid < 8){
        // fps1: 256 -> 64 (multi-wave, 1 pt/thread, r14-proven body)
        float4* sxyz = (float4*)LB;
        const float* X2 = xyz2 + (size_t)bid * 3 * 256;
        for (int t = tid; t < 256; t += 256)
            sxyz[t] = make_float4(X2[t], X2[256 + t], X2[512 + t], 0.f);
        float s1x = X2[tid], s1y = X2[256 + tid], s1z = X2[512 + tid], s1d = 1e10f;
        asm volatile("" : "+v"(s1x), "+v"(s1y), "+v"(s1z));
        float* NX_ = xyz3 + (size_t)bid * 3 * 64;
        if (tid == 0){ NX_[0] = X2[0]; NX_[64] = X2[256]; NX_[128] = X2[512]; }
        float lx = X2[0], ly = X2[256], lz = X2[512];
        __syncthreads();
        for (int i = 1; i < 64; ++i){
            float dx = s1x - lx, dy = s1y - ly, dz = s1z - lz;
            float dd = fmaf(dz, dz, fmaf(dy, dy, dx*dx));
            float nd = fminf(s1d, dd); s1d = nd;
            unsigned long long bp = ((unsigned long long)__float_as_uint(nd) << 32) | (unsigned)~tid;
            DPP_REDUCE2(bp)
            FPS_COMBINE(i)
            lx = wn.x; ly = wn.y; lz = wn.z;
            if (tid == 0){ NX_[i] = wn.x; NX_[64 + i] = wn.y; NX_[128 + i] = wn.z; }
        }
    } else if (bid < 520){
        int t = bid - 8;
        dev_res(t >> 6, (t & 63) << 6, 4096, dm4b, pm4b, idx4,
                wT + 1 * 4096, wT + 3 * 4096, dm4a, pm4a, (float (*)[65])LB);
    } else if (bid < 528){
        dev_knn(bid - 520, 0, xyz2, 256, xyz1, 1024, i256p, (float4*)LB);
    } else {
        dev_knn(bid - 528, 0, xyz2, 256, xyz2, 256, i256s, (float4*)LB);
    }
}

// ================= LAUNCH 4: pool1024 || knn(64,256) || knn(64,64) =================
__global__ void __launch_bounds__(256, 1)
k_mid3(const float* __restrict__ xyz2, const float* __restrict__ xyz3,
       const float* __restrict__ pm4a, const int* __restrict__ i1024p,
       float* __restrict__ dm1a, float* __restrict__ pm1a,
       int* __restrict__ i64p, int* __restrict__ i64s){
    __shared__ __align__(16) char LB[16640];
    int bid = blockIdx.x;
    if (bid < 128){
        dev_pool(bid >> 4, (bid & 15) << 6, 1024, 4096, pm4a, i1024p,
                 dm1a, pm1a, (float (*)[65])LB);
    } else if (bid < 136){
        dev_knn(bid - 128, 0, xyz3, 64, xyz2, 256, i64p, (float4*)LB);
    } else {
        dev_knn(bid - 136, 0, xyz3, 64, xyz3, 64, i64s, (float4*)LB);
    }
}

// ================= generic res / pool launches =================
__global__ void __launch_bounds__(256, 1)
k_res_g(const float* __restrict__ dmc, const float* __restrict__ pmc,
        const int* __restrict__ idx, const float* __restrict__ wc_,
        const float* __restrict__ wg_, float* __restrict__ dmo,
        float* __restrict__ pmo, int n){
    __shared__ float tile[64][65];
    int tiles = n >> 6;
    int b = blockIdx.x / tiles, j0 = (blockIdx.x % tiles) << 6;
    dev_res(b, j0, n, dmc, pmc, idx, wc_, wg_, dmo, pmo, tile);
}

__global__ void __launch_bounds__(256, 1)
k_pool_g(const float* __restrict__ pmc, const int* __restrict__ idx,
         float* __restrict__ dmo, float* __restrict__ pmo, int np, int nsrc){
    __shared__ float tile[64][65];
    int tiles = np >> 6;
    int b = blockIdx.x / tiles, m0 = (blockIdx.x % tiles) << 6;
    dev_pool(b, m0, np, nsrc, pmc, idx, dmo, pmo, tile);
}

// ================= tail: pool64 + 4x res64 (in-LDS) + final, 1 block/batch =================
#define RC_FINL64(i) a##i = a##i * inv + pmX[lane][w16 + (i)];
#define RC_WL64(i)   pmX[lane][w16 + (i)] = a##i;

__device__ __forceinline__ void res_lds64g(float (*pmX)[65], float (*S)[65],
        const int* idg, const float* __restrict__ wcT, const float* __restrict__ wgT,
        int lane, int w){
    for (int c = 0; c < 16; ++c){
        int col = w * 16 + c;
        const int* id = idg + col * 8;
        float v = 0.f;
        #pragma unroll
        for (int k = 0; k < 8; ++k) v += leaky(pmX[id[k]][lane]);
        S[col][lane] = v;
    }
    __syncthreads();
    int w16 = w * 16;
    RPT16(RC_DECL)
    #pragma unroll 2
    for (int d = 0; d < 64; ++d){
        float h  = leaky(pmX[lane][d]);
        float sv = S[lane][d];
        const float* wc = wcT + d * 64 + w16;
        const float* wg = wgT + d * 64 + w16;
        RPT16(RC_FMA)
    }
    const float inv = 1.0f / 9.0f;
    RPT16(RC_FINL64)
    __syncthreads();
    RPT16(RC_WL64)
    __syncthreads();
}

__global__ void __launch_bounds__(256, 1)
k_tail64(const float* __restrict__ pm2a, const int* __restrict__ i64p,
         const int* __restrict__ i64s, const float* __restrict__ wT,
         const float* __restrict__ wl, float* __restrict__ out){
    __shared__ float pm64[64][65];
    __shared__ float S64[64][65];
    int b = blockIdx.x, tid = threadIdx.x;
    int lane = tid & 63, w = tid >> 6;
    // pool64 from global pm@256 (point-major)
    const float* PM = pm2a + (size_t)b * 256 * 64;
    const int* idp = i64p + (size_t)b * 64 * 8;
    for (int c = 0; c < 16; ++c){
        int col = w * 16 + c;
        const int* id = idp + col * 8;
        float v = -FLT_MAX;
        #pragma unroll
        for (int k = 0; k < 8; ++k)
            v = fmaxf(v, PM[(size_t)id[k] * 64 + lane]);
        pm64[col][lane] = v;
    }
    __syncthreads();
    const int* ids = i64s + (size_t)b * 64 * 8;
    for (int L = 0; L < 4; ++L)
        res_lds64g(pm64, S64, ids, wT + (size_t)(12 + L) * 4096,
                   wT + (size_t)(24 + L) * 4096, lane, w);
    if (tid < 64){
        float acc = 0.f;
        for (int d = 0; d < 64; ++d) acc += wl[d] * leaky(pm64[tid][d]);
        out[(size_t)b * 64 + tid] = acc;
    }
}

extern "C" void kernel_launch(void* const* d_in, const int* in_sizes, int n_in,
                              void* d_out, int out_size, void* d_ws, size_t ws_size,
                              hipStream_t stream){
    const float* xyz_in  = (const float*)d_in[0];
    const float* w0      = (const float*)d_in[1];
    const float* fn_wc   = (const float*)d_in[2];
    const float* fn_wg   = (const float*)d_in[3];
    const float* res_wc  = (const float*)d_in[4];
    const float* res_wg  = (const float*)d_in[5];
    const float* w_last  = (const float*)d_in[6];
    float* out = (float*)d_out;
    char* ws = (char*)d_ws;

    float* wT    = (float*)(ws + 0UL);
    float* dm4a  = (float*)(ws + 458752UL);
    float* dm4b  = (float*)(ws + 8847360UL);
    float* pm4a  = (float*)(ws + 17235968UL);
    float* pm4b  = (float*)(ws + 25624576UL);
    int*   idx4  = (int*)  (ws + 34013184UL);
    float* xyz1  = (float*)(ws + 35061760UL);
    float* xyz2  = (float*)(ws + 35160064UL);
    float* xyz3  = (float*)(ws + 35184640UL);
    int* i1024p  = (int*)(ws + 35190784UL);
    int* i1024s  = (int*)(ws + 35452928UL);
    int* i256p   = (int*)(ws + 35715072UL);
    int* i256s   = (int*)(ws + 35780608UL);
    int* i64p    = (int*)(ws + 35846144UL);
    int* i64s    = (int*)(ws + 35862528UL);
    // level buffers aliased into dm4b/pm4b (dead after k_mid2)
    float* dm1a = (float*)((char*)dm4b + 0UL);
    float* dm1b = (float*)((char*)dm4b + 2097152UL);
    float* dm2a = (float*)((char*)dm4b + 4194304UL);
    float* dm2b = (float*)((char*)dm4b + 4718592UL);
    float* pm1a = (float*)((char*)pm4b + 0UL);
    float* pm1b = (float*)((char*)pm4b + 2097152UL);
    float* pm2a = (float*)((char*)pm4b + 4194304UL);
    float* pm2b = (float*)((char*)pm4b + 4718592UL);

    // L1: fps16 || knn@4096 || transpose || conv0
    k_front<<<228, 256, 0, stream>>>(xyz_in, w0, fn_wc, fn_wg, res_wc, res_wg,
                                     wT, dm4a, pm4a, idx4, xyz1);
    // L2: fps4 || res4096#1 || knn(1024,4096) || knn(1024,1024)
    k_mid1<<<584, 256, 0, stream>>>(xyz_in, xyz1, wT, dm4a, pm4a, idx4,
                                    dm4b, pm4b, i1024p, i1024s, xyz2);
    // L3: fps1 || res4096#2 || knn(256,1024) || knn(256,256)
    k_mid2<<<536, 256, 0, stream>>>(xyz1, xyz2, wT, dm4b, pm4b, idx4,
                                    dm4a, pm4a, i256p, i256s, xyz3);
    // L4: pool1024 || knn(64,256) || knn(64,64)
    k_mid3<<<144, 256, 0, stream>>>(xyz2, xyz3, pm4a, i1024p, dm1a, pm1a, i64p, i64s);
    // L5-8: res@1024 x4
    k_res_g<<<128, 256, 0, stream>>>(dm1a, pm1a, i1024s, wT + 4*4096, wT + 16*4096, dm1b, pm1b, 1024);
    k_res_g<<<128, 256, 0, stream>>>(dm1b, pm1b, i1024s, wT + 5*4096, wT + 17*4096, dm1a, pm1a, 1024);
    k_res_g<<<128, 256, 0, stream>>>(dm1a, pm1a, i1024s, wT + 6*4096, wT + 18*4096, dm1b, pm1b, 1024);
    k_res_g<<<128, 256, 0, stream>>>(dm1b, pm1b, i1024s, wT + 7*4096, wT + 19*4096, dm1a, pm1a, 1024);
    // L9: pool@256
    k_pool_g<<<32, 256, 0, stream>>>(pm1a, i256p, dm2a, pm2a, 256, 1024);
    // L10-13: res@256 x4
    k_res_g<<<32, 256, 0, stream>>>(dm2a, pm2a, i256s, wT + 8*4096,  wT + 20*4096, dm2b, pm2b, 256);
    k_res_g<<<32, 256, 0, stream>>>(dm2b, pm2b, i256s, wT + 9*4096,  wT + 21*4096, dm2a, pm2a, 256);
    k_res_g<<<32, 256, 0, stream>>>(dm2a, pm2a, i256s, wT + 10*4096, wT + 22*4096, dm2b, pm2b, 256);
    k_res_g<<<32, 256, 0, stream>>>(dm2b, pm2b, i256s, wT + 11*4096, wT + 23*4096, dm2a, pm2a, 256);
    // L14: pool64 + res@64 x4 + final (in-LDS)
    k_tail64<<<8, 256, 0, stream>>>(pm2a, i64p, i64s, wT, w_last, out);
}